// Round 10
// baseline (347.857 us; speedup 1.0000x reference)
//
#include <hip/hip_runtime.h>

typedef unsigned int u32;
typedef unsigned short u16;
typedef __attribute__((ext_vector_type(4))) float f32x4;
typedef __attribute__((ext_vector_type(8))) short s16x8;
typedef __attribute__((ext_vector_type(4))) u32 u32x4;

#define DIMN 128
#define MATN (DIMN*DIMN)
#define NA 8
#define LSEQ 8192
#define NTOK (LSEQ/2)
#define PITERS 4
#define S1SH 5
#define S2SH 6
#define CHSH 7
#define P2SH 8
#define GCH 256
#define GLG 16

struct WS {
  u16 *Kb, *P2b, *rho, *nodes0, *nodes1, *rootR, *rootI;
  int *tok, *E0, *E1, *Eroot;
  float *trbuf;
  float *out;
};

__device__ __forceinline__ u16 f2bf(float x){
  u32 u = __float_as_uint(x);
  u32 r = (u + 0x7FFFu + ((u >> 16) & 1u)) >> 16;
  return (u16)r;
}
__device__ __forceinline__ float bf2f(u16 u){ return __uint_as_float(((u32)u) << 16); }
__device__ __forceinline__ u32 cvtpk(float lo, float hi){
  u32 r; asm("v_cvt_pk_bf16_f32 %0, %1, %2" : "=v"(r) : "v"(lo), "v"(hi)); return r;
}
__device__ __forceinline__ s16x8 negi(s16x8 v){
  return __builtin_bit_cast(s16x8, __builtin_bit_cast(u32x4, v) ^ 0x80008000u);
}
__device__ __forceinline__ int swz16(int maj, int b){
  return maj*256 + (((((b >> 4) + maj*5) & 15) << 4) | (b & 15));
}
__device__ __forceinline__ void cfma2(float2& c, float2 a, float2 b){
  c.x = fmaf(a.x, b.x, c.x); c.x = fmaf(-a.y, b.y, c.x);
  c.y = fmaf(a.x, b.y, c.y); c.y = fmaf(a.y, b.x, c.y);
}
template<int CA, int CB>
__device__ __forceinline__ void cmfma(s16x8 a_r, s16x8 a_i, s16x8 b_r, s16x8 b_i,
                                      f32x4& qr, f32x4& qi){
  s16x8 t1 = (CA ^ CB) ? a_i : negi(a_i);
  s16x8 t2 = CB ? negi(a_r) : a_r;
  s16x8 t3 = CA ? negi(a_i) : a_i;
  qr = __builtin_amdgcn_mfma_f32_16x16x32_bf16(a_r, b_r, qr, 0,0,0);
  qr = __builtin_amdgcn_mfma_f32_16x16x32_bf16(t1,  b_i, qr, 0,0,0);
  qi = __builtin_amdgcn_mfma_f32_16x16x32_bf16(t2,  b_i, qi, 0,0,0);
  qi = __builtin_amdgcn_mfma_f32_16x16x32_bf16(t3,  b_r, qi, 0,0,0);
}

// ----------------- k_kbinit: Kb bf16 planes + tokens + rho + trbuf ----------
__global__ __launch_bounds__(256) void k_kbinit(const float* Kre, const float* Kim,
                                                const int* seq, WS w){
  __shared__ u16 Lr[32][36], Li[32][36];
  int blk = blockIdx.x, x = blk >> 4, tile = blk & 15;
  int row0 = (tile>>2)*32, col0 = (tile&3)*32;
  int t = threadIdx.x;
  { int r = t>>3, cch = t&7;
    size_t off = (size_t)x*MATN + (size_t)(row0+r)*128 + col0 + cch*4;
    float4 vr = *(const float4*)(Kre + off);
    float4 vi = *(const float4*)(Kim + off);
    Lr[r][cch*4+0] = f2bf(vr.x); Lr[r][cch*4+1] = f2bf(vr.y);
    Lr[r][cch*4+2] = f2bf(vr.z); Lr[r][cch*4+3] = f2bf(vr.w);
    Li[r][cch*4+0] = f2bf(vi.x); Li[r][cch*4+1] = f2bf(vi.y);
    Li[r][cch*4+2] = f2bf(vi.z); Li[r][cch*4+3] = f2bf(vi.w);
  }
  __syncthreads();
  u16* b = w.Kb + (size_t)x*4*MATN;
  { int r = t>>3, cch = t&7;
    *(uint2*)&b[(row0+r)*128 + col0 + cch*4]        = *(uint2*)&Lr[r][cch*4];
    *(uint2*)&b[MATN + (row0+r)*128 + col0 + cch*4] = *(uint2*)&Li[r][cch*4];
  }
  { int c = t>>3, rch = t&7;
    ushort4 vr, vi;
    vr.x = Lr[rch*4+0][c]; vr.y = Lr[rch*4+1][c];
    vr.z = Lr[rch*4+2][c]; vr.w = Lr[rch*4+3][c];
    vi.x = Li[rch*4+0][c]; vi.y = Li[rch*4+1][c];
    vi.z = Li[rch*4+2][c]; vi.w = Li[rch*4+3][c];
    *(ushort4*)&b[2*MATN + (col0+c)*128 + row0 + rch*4] = vr;
    *(ushort4*)&b[3*MATN + (col0+c)*128 + row0 + rch*4] = vi;
  }
  int gid = blockIdx.x*256 + t, gsz = gridDim.x*256;
  for (int i = gid; i < NTOK; i += gsz)
    w.tok[i] = seq[2*i+1]*NA + seq[2*i];
  for (int i = gid; i < 4*MATN; i += gsz){
    int plane = (i >> 14) & 1, rem = i & (MATN-1);
    u16 v = (plane == 0 && (rem >> 7) == (rem & 127)) ? f2bf(1.f) : (u16)0;
    w.rho[i] = v;
  }
  if (gid < 32) w.trbuf[gid] = 0.f;
}

// ----------------- k_p2: fp32 gemm, coalesced bf16 plane store (R8) ---------
__global__ __launch_bounds__(256) void k_p2(const float* Kre, const float* Kim, WS w){
  __shared__ float2 As[16][33], Bs[16][33];
  int blk = blockIdx.x, mat = blk >> 4, tile = blk & 15;
  int a = mat >> 3, b = mat & 7;
  int row0 = (tile>>2)*32, col0 = (tile&3)*32;
  int t = threadIdx.x, ti = t & 15, tk = t >> 4;
  float2 acc[4] = {{0,0},{0,0},{0,0},{0,0}};
  for (int k0 = 0; k0 < 128; k0 += 16){
    { int r = t >> 4, kk = t & 15;
      size_t i0 = (size_t)a*MATN + (size_t)(row0+r)*DIMN + k0+kk;
      size_t i1 = i0 + 16*DIMN;
      As[kk][r]    = make_float2(Kre[i0], Kim[i0]);
      As[kk][r+16] = make_float2(Kre[i1], Kim[i1]); }
    { int kk = t >> 5, c = t & 31;
      size_t i0 = (size_t)b*MATN + (size_t)(k0+kk)*DIMN + col0+c;
      size_t i1 = i0 + 8*DIMN;
      Bs[kk][c]   = make_float2(Kre[i0], Kim[i0]);
      Bs[kk+8][c] = make_float2(Kre[i1], Kim[i1]); }
    __syncthreads();
    #pragma unroll
    for (int jj = 0; jj < 16; jj++){
      float2 a0 = As[jj][ti], a1 = As[jj][ti+16];
      float2 b0 = Bs[jj][tk], b1 = Bs[jj][tk+16];
      cfma2(acc[0], a0, b0); cfma2(acc[1], a0, b1);
      cfma2(acc[2], a1, b0); cfma2(acc[3], a1, b1);
    }
    __syncthreads();
  }
  u16* Lr = (u16*)As; u16* Li = (u16*)Bs;   // [32][36]
  const float sc = 1.f/(1<<P2SH);
  Lr[ti*36+tk]         = f2bf(acc[0].x*sc); Li[ti*36+tk]         = f2bf(acc[0].y*sc);
  Lr[ti*36+tk+16]      = f2bf(acc[1].x*sc); Li[ti*36+tk+16]      = f2bf(acc[1].y*sc);
  Lr[(ti+16)*36+tk]    = f2bf(acc[2].x*sc); Li[(ti+16)*36+tk]    = f2bf(acc[2].y*sc);
  Lr[(ti+16)*36+tk+16] = f2bf(acc[3].x*sc); Li[(ti+16)*36+tk+16] = f2bf(acc[3].y*sc);
  __syncthreads();
  u16* base = w.P2b + (size_t)mat*4*MATN;
  { int r = t>>3, cch = t&7;
    *(uint2*)&base[(row0+r)*128 + col0 + cch*4]        = *(uint2*)&Lr[r*36 + cch*4];
    *(uint2*)&base[MATN + (row0+r)*128 + col0 + cch*4] = *(uint2*)&Li[r*36 + cch*4];
  }
  { int c = t>>3, rch = t&7;
    ushort4 vr, vi;
    vr.x = Lr[(rch*4+0)*36 + c]; vr.y = Lr[(rch*4+1)*36 + c];
    vr.z = Lr[(rch*4+2)*36 + c]; vr.w = Lr[(rch*4+3)*36 + c];
    vi.x = Li[(rch*4+0)*36 + c]; vi.y = Li[(rch*4+1)*36 + c];
    vi.z = Li[(rch*4+2)*36 + c]; vi.w = Li[(rch*4+3)*36 + c];
    *(ushort4*)&base[2*MATN + (col0+c)*128 + row0 + rch*4] = vr;
    *(ushort4*)&base[3*MATN + (col0+c)*128 + row0 + rch*4] = vi;
  }
}

// ------- chain/level machinery: 8 waves (4 row x 2 col), A in regs ----------
__device__ __forceinline__ void loadA(const u16* Ar, const u16* Ai,
    int wr, int l15, int hi, s16x8 (&fr)[4][2], s16x8 (&fi)[4][2]){
  #pragma unroll
  for (int kk = 0; kk < 4; kk++){
    int kb = kk*32 + hi*8;
    #pragma unroll
    for (int m = 0; m < 2; m++){
      int r = wr + m*16 + l15;
      fr[kk][m] = *(const s16x8*)(Ar + r*128 + kb);
      fi[kk][m] = *(const s16x8*)(Ai + r*128 + kb);
    }
  }
}
__device__ __forceinline__ void ccomputeR(const s16x8 (&fr)[4][2], const s16x8 (&fi)[4][2],
    const char* Pr, const char* Pi, f32x4 (&qr)[2][4], f32x4 (&qi)[2][4],
    int wc, int l15, int hi){
  #pragma unroll
  for (int m=0;m<2;m++)
    #pragma unroll
    for (int n=0;n<4;n++){ qr[m][n] = (f32x4){0,0,0,0}; qi[m][n] = (f32x4){0,0,0,0}; }
  #pragma unroll
  for (int kk = 0; kk < 4; kk++){
    int kb = kk*32 + hi*8;
    #pragma unroll
    for (int n=0;n<4;n++){
      int c = wc + n*16 + l15;
      int o = swz16(c, kb*2);
      s16x8 b_r = *(const s16x8*)(Pr + o);
      s16x8 b_i = *(const s16x8*)(Pi + o);
      #pragma unroll
      for (int m=0;m<2;m++)
        cmfma<0,0>(fr[kk][m], fi[kk][m], b_r, b_i, qr[m][n], qi[m][n]);
    }
  }
}
__device__ __forceinline__ void pwrite16(char* Pr, char* Pi,
    f32x4 (&qr)[2][4], f32x4 (&qi)[2][4], float sc, int t){
  int wv = t>>6, lane = t&63, l15 = lane&15, hi = lane>>4;
  int wr = (wv>>1)*32, wc = (wv&1)*64;
  #pragma unroll
  for (int m=0;m<2;m++)
    #pragma unroll
    for (int n=0;n<4;n++){
      int c = wc + n*16 + l15, r0 = wr + m*16 + hi*4;
      uint2 pr, pi;
      pr.x = cvtpk(qr[m][n][0]*sc, qr[m][n][1]*sc);
      pr.y = cvtpk(qr[m][n][2]*sc, qr[m][n][3]*sc);
      pi.x = cvtpk(qi[m][n][0]*sc, qi[m][n][1]*sc);
      pi.y = cvtpk(qi[m][n][2]*sc, qi[m][n][3]*sc);
      int o = swz16(c, r0*2);
      *(uint2*)(Pr + o) = pr;
      *(uint2*)(Pi + o) = pi;
    }
}
// max-renorm into DEST buffers (dbuf-safe); one internal barrier via red[]
__device__ __forceinline__ int renorm_to(char* Pr, char* Pi, float* red,
    f32x4 (&qr)[2][4], f32x4 (&qi)[2][4], int t){
  int wv = t>>6, lane = t&63;
  float lm = 0.f;
  #pragma unroll
  for (int m=0;m<2;m++)
    #pragma unroll
    for (int n=0;n<4;n++)
      #pragma unroll
      for (int j=0;j<4;j++)
        lm = fmaxf(lm, fmaxf(fabsf(qr[m][n][j]), fabsf(qi[m][n][j])));
  #pragma unroll
  for (int o = 32; o > 0; o >>= 1) lm = fmaxf(lm, __shfl_xor(lm, o, 64));
  if (lane == 0) red[wv] = lm;
  __syncthreads();
  float mx = 0.f;
  #pragma unroll
  for (int i = 0; i < 8; i++) mx = fmaxf(mx, red[i]);
  int e = 0; if (mx > 0.f) frexpf(mx, &e);
  pwrite16(Pr, Pi, qr, qi, ldexpf(1.f, -e), t);
  return e;
}
__device__ __forceinline__ void stage_cols16(const u16* gr, const u16* gi,
                                             char* Pr, char* Pi, int t){
  #pragma unroll
  for (int i = 0; i < 4; i++){
    int chunk = t + i*512;
    int c = chunk >> 4, rr = chunk & 15;
    int o = swz16(c, rr*16);
    *(uint4*)(Pr + o) = *(const uint4*)(gr + c*128 + rr*8);
    *(uint4*)(Pi + o) = *(const uint4*)(gi + c*128 + rr*8);
  }
}
__device__ __forceinline__ void write_node16(u16* dr, u16* di,
    const char* Pr, const char* Pi, bool rowLayout, int t){
  if (!rowLayout){
    #pragma unroll
    for (int i = 0; i < 4; i++){
      int chunk = t + i*512;
      int c = chunk >> 4, rr = chunk & 15;
      int o = swz16(c, rr*16);
      *(uint4*)(dr + c*128 + rr*8) = *(const uint4*)(Pr + o);
      *(uint4*)(di + c*128 + rr*8) = *(const uint4*)(Pi + o);
    }
  } else {
    for (int idx = t; idx < MATN; idx += 512){
      int r = idx >> 7, c = idx & 127;
      int o = swz16(c, r*2);
      dr[idx] = *(const u16*)(Pr + o);
      di[idx] = *(const u16*)(Pi + o);
    }
  }
}

// chains: 256 blocks, 15 products; LDS dbuf + reg A-prefetch, 1 barrier/step
__global__ __launch_bounds__(512,1) void k_chain(WS w){
  __shared__ __align__(16) char P0r[32768];
  __shared__ __align__(16) char P0i[32768];
  __shared__ __align__(16) char P1r[32768];
  __shared__ __align__(16) char P1i[32768];
  __shared__ float red[8];
  int p = blockIdx.x, t = threadIdx.x;
  int wv = t>>6, lane = t&63, l15 = lane&15, hi = lane>>4;
  int wr = (wv>>1)*32, wc = (wv&1)*64;
  char *PrC = P0r, *PiC = P0i, *PrN = P1r, *PiN = P1i;
  int tok0 = w.tok[p*GLG];
  const u16* b0 = w.P2b + (size_t)tok0*4*MATN;
  stage_cols16(b0 + 2*MATN, b0 + 3*MATN, PrC, PiC, t);
  s16x8 A1r[4][2], A1i[4][2], A2r[4][2], A2i[4][2];
  { const u16* tb = w.P2b + (size_t)w.tok[p*GLG + 1]*4*MATN;
    loadA(tb, tb + MATN, wr, l15, hi, A1r, A1i); }
  f32x4 qr[2][4], qi[2][4];
  int eLast = 0;
  __syncthreads();
  #pragma unroll 1
  for (int s = 1; s < GLG; s += 2){
    if (s+1 < GLG){
      const u16* tb = w.P2b + (size_t)w.tok[p*GLG + s+1]*4*MATN;
      loadA(tb, tb + MATN, wr, l15, hi, A2r, A2i);
    }
    ccomputeR(A1r, A1i, PrC, PiC, qr, qi, wc, l15, hi);
    if (s < GLG-1) pwrite16(PrN, PiN, qr, qi, 1.f/(1<<CHSH), t);
    else eLast = renorm_to(PrN, PiN, red, qr, qi, t);
    __syncthreads();
    { char* x = PrC; PrC = PrN; PrN = x; x = PiC; PiC = PiN; PiN = x; }
    if (s+1 < GLG){
      if (s+2 < GLG){
        const u16* tb = w.P2b + (size_t)w.tok[p*GLG + s+2]*4*MATN;
        loadA(tb, tb + MATN, wr, l15, hi, A1r, A1i);
      }
      ccomputeR(A2r, A2i, PrC, PiC, qr, qi, wc, l15, hi);
      if (s+1 < GLG-1) pwrite16(PrN, PiN, qr, qi, 1.f/(1<<CHSH), t);
      else eLast = renorm_to(PrN, PiN, red, qr, qi, t);
      __syncthreads();
      { char* x = PrC; PrC = PrN; PrN = x; x = PiC; PiC = PiN; PiN = x; }
    }
  }
  u16* slot = w.nodes0 + (size_t)p*2*MATN;
  write_node16(slot, slot + MATN, PrC, PiC, (p & 3) != 0, t);
  if (t == 0) w.E0[p] = P2SH*GLG + CHSH*(GLG-2) + eLast;
}

// radix-4 level: dbuf + prefetch; renorm each product
__global__ __launch_bounds__(512,1) void k_level(WS w, int srcIs0, int isRoot){
  __shared__ __align__(16) char P0r[32768];
  __shared__ __align__(16) char P0i[32768];
  __shared__ __align__(16) char P1r[32768];
  __shared__ __align__(16) char P1i[32768];
  __shared__ float red[8];
  int p = blockIdx.x, t = threadIdx.x;
  int wv = t>>6, lane = t&63, l15 = lane&15, hi = lane>>4;
  int wr = (wv>>1)*32, wc = (wv&1)*64;
  char *PrC = P0r, *PiC = P0i, *PrN = P1r, *PiN = P1i;
  const u16* src = srcIs0 ? w.nodes0 : w.nodes1;
  u16* dst       = srcIs0 ? w.nodes1 : w.nodes0;
  const int* Es  = srcIs0 ? w.E0 : w.E1;
  int* Ed        = srcIs0 ? w.E1 : w.E0;
  const u16* B = src + (size_t)(4*p)*2*MATN;
  stage_cols16(B, B + MATN, PrC, PiC, t);
  s16x8 A1r[4][2], A1i[4][2], A2r[4][2], A2i[4][2];
  { const u16* A = src + (size_t)(4*p+1)*2*MATN;
    loadA(A, A + MATN, wr, l15, hi, A1r, A1i); }
  int E = Es[4*p] + Es[4*p+1] + Es[4*p+2] + Es[4*p+3];
  f32x4 qr[2][4], qi[2][4];
  __syncthreads();
  { const u16* A = src + (size_t)(4*p+2)*2*MATN;
    loadA(A, A + MATN, wr, l15, hi, A2r, A2i); }
  ccomputeR(A1r, A1i, PrC, PiC, qr, qi, wc, l15, hi);
  E += renorm_to(PrN, PiN, red, qr, qi, t);
  __syncthreads();
  { char* x = PrC; PrC = PrN; PrN = x; x = PiC; PiC = PiN; PiN = x; }
  { const u16* A = src + (size_t)(4*p+3)*2*MATN;
    loadA(A, A + MATN, wr, l15, hi, A1r, A1i); }
  ccomputeR(A2r, A2i, PrC, PiC, qr, qi, wc, l15, hi);
  E += renorm_to(PrN, PiN, red, qr, qi, t);
  __syncthreads();
  { char* x = PrC; PrC = PrN; PrN = x; x = PiC; PiC = PiN; PiN = x; }
  ccomputeR(A1r, A1i, PrC, PiC, qr, qi, wc, l15, hi);
  E += renorm_to(PrN, PiN, red, qr, qi, t);
  __syncthreads();
  { char* x = PrC; PrC = PrN; PrN = x; x = PiC; PiC = PiN; PiN = x; }
  u16* slot = dst + (size_t)p*2*MATN;
  write_node16(slot, slot + MATN, PrC, PiC, ((p & 3) != 0) || isRoot, t);
  if (t == 0) Ed[p] = E;
}

// -------- fused power iteration (R8 verbatim) --------
__global__ __launch_bounds__(512,1) void k_pow(WS w, int par){
  __shared__ __align__(16) char Rr[32768];
  __shared__ __align__(16) char Ri[32768];
  __shared__ __align__(16) char Yr[32768];
  __shared__ __align__(16) char Yi[32768];
  int b = blockIdx.x, side = b >> 3, rb = b & 7;
  int t = threadIdx.x, wv = t>>6, lane = t&63, l15 = lane&15, hi = lane>>4;
  const u16* rhoS = w.rho + (size_t)((par*2 + side)*2)*MATN;
  stage_cols16(rhoS, rhoS + MATN, Rr, Ri, t);
  __syncthreads();
  { int x = wv;
    const u16* Ab = w.Kb + (size_t)(x*4 + (side ? 2 : 0))*MATN;
    const u16* Ar = Ab; const u16* Ai = Ab + MATN;
    f32x4 q1r[8], q1i[8];
    #pragma unroll
    for (int n=0;n<8;n++){ q1r[n] = (f32x4){0,0,0,0}; q1i[n] = (f32x4){0,0,0,0}; }
    #pragma unroll
    for (int kk = 0; kk < 4; kk++){
      int kb = kk*32 + hi*8;
      int r = rb*16 + l15;
      s16x8 a_r = *(const s16x8*)(Ar + r*128 + kb);
      s16x8 a_i = *(const s16x8*)(Ai + r*128 + kb);
      #pragma unroll
      for (int n=0;n<8;n++){
        int c = n*16 + l15;
        int o = swz16(c, kb*2);
        s16x8 b_r = *(const s16x8*)(Rr + o);
        s16x8 b_i = *(const s16x8*)(Ri + o);
        if (side == 0) cmfma<0,0>(a_r, a_i, b_r, b_i, q1r[n], q1i[n]);
        else           cmfma<1,0>(a_r, a_i, b_r, b_i, q1r[n], q1i[n]);
      }
    }
    const float sc = 1.f/(1<<S1SH);
    #pragma unroll
    for (int n=0;n<8;n++)
      #pragma unroll
      for (int q=0;q<4;q++){
        int lr = hi*4 + q, c = n*16 + l15;
        *(u16*)(Yr + x*4096 + swz16(lr, c*2)) = f2bf(q1r[n][q]*sc);
        *(u16*)(Yi + x*4096 + swz16(lr, c*2)) = f2bf(q1i[n][q]*sc);
      }
  }
  __syncthreads();
  { int c0 = wv*16, c = c0 + l15;
    f32x4 q2r = {0,0,0,0}, q2i = {0,0,0,0};
    #pragma unroll 2
    for (int x = 0; x < 8; x++){
      const u16* Bb = w.Kb + (size_t)(x*4 + (side ? 2 : 0))*MATN;
      const u16* Br = Bb; const u16* Bi = Bb + MATN;
      #pragma unroll
      for (int kk = 0; kk < 4; kk++){
        int kb = kk*32 + hi*8;
        s16x8 a_r = *(const s16x8*)(Yr + x*4096 + swz16(l15, kb*2));
        s16x8 a_i = *(const s16x8*)(Yi + x*4096 + swz16(l15, kb*2));
        s16x8 b_r = *(const s16x8*)(Br + c*128 + kb);
        s16x8 b_i = *(const s16x8*)(Bi + c*128 + kb);
        if (side == 0) cmfma<0,1>(a_r, a_i, b_r, b_i, q2r, q2i);
        else           cmfma<0,0>(a_r, a_i, b_r, b_i, q2r, q2i);
      }
    }
    const float sc = 1.f/(1<<S2SH);
    u16* Dr = w.rho + (size_t)(((par^1)*2 + side)*2)*MATN;
    u16* Di = Dr + MATN;
    int r0g = rb*16 + hi*4;
    uint2 pr, pi;
    pr.x = cvtpk(q2r[0]*sc, q2r[1]*sc); pr.y = cvtpk(q2r[2]*sc, q2r[3]*sc);
    pi.x = cvtpk(q2i[0]*sc, q2i[1]*sc); pi.y = cvtpk(q2i[2]*sc, q2i[3]*sc);
    *(uint2*)(Dr + c*128 + r0g) = pr;
    *(uint2*)(Di + c*128 + r0g) = pi;
    if (side == 1 && wv == rb){
      float tr = 0.f;
      #pragma unroll
      for (int q=0;q<4;q++) if (hi*4 + q == l15) tr += q2r[q]*sc;
      #pragma unroll
      for (int o = 32; o > 0; o >>= 1) tr += __shfl_xor(tr, o, 64);
      if (lane == 0) w.trbuf[par*16 + 8 + rb] = tr;
    }
  }
}

// ----------------- fused epilogue (R8 verbatim) -----------------
__global__ __launch_bounds__(512) void k_epi(WS w){
  __shared__ __align__(16) char T1r[32768];
  __shared__ __align__(16) char T1i[32768];
  int t = threadIdx.x, wv = t>>6, lane = t&63, l15 = lane&15, hi = lane>>4;
  int wr = (wv>>2)*64, wc = (wv&3)*32;
  f32x4 qr[4][2], qi[4][2];
  const u16* Ar = w.rho;
  const u16* Ai = Ar + MATN;
  #pragma unroll
  for (int m=0;m<4;m++)
    #pragma unroll
    for (int n=0;n<2;n++){ qr[m][n] = (f32x4){0,0,0,0}; qi[m][n] = (f32x4){0,0,0,0}; }
  #pragma unroll
  for (int kk = 0; kk < 4; kk++){
    int kb = kk*32 + hi*8;
    #pragma unroll
    for (int m=0;m<4;m++){
      int r = wr + m*16 + l15;
      s16x8 a_r = *(const s16x8*)(Ar + r*128 + kb);
      s16x8 a_i = *(const s16x8*)(Ai + r*128 + kb);
      #pragma unroll
      for (int n=0;n<2;n++){
        int c = wc + n*16 + l15;
        s16x8 b_r = *(const s16x8*)(w.rootR + c*128 + kb);
        s16x8 b_i = *(const s16x8*)(w.rootI + c*128 + kb);
        cmfma<0,0>(a_r, a_i, b_r, b_i, qr[m][n], qi[m][n]);
      }
    }
  }
  {
    const float sc = 1.f/(1<<CHSH);
    #pragma unroll
    for (int m=0;m<4;m++)
      #pragma unroll
      for (int n=0;n<2;n++){
        int c = wc + n*16 + l15, r0 = wr + m*16 + hi*4;
        uint2 pr, pi;
        pr.x = cvtpk(qr[m][n][0]*sc, qr[m][n][1]*sc);
        pr.y = cvtpk(qr[m][n][2]*sc, qr[m][n][3]*sc);
        pi.x = cvtpk(qi[m][n][0]*sc, qi[m][n][1]*sc);
        pi.y = cvtpk(qi[m][n][2]*sc, qi[m][n][3]*sc);
        int o = swz16(c, r0*2);
        *(uint2*)(T1r + o) = pr;
        *(uint2*)(T1i + o) = pi;
      }
  }
  __syncthreads();
  #pragma unroll
  for (int m=0;m<4;m++)
    #pragma unroll
    for (int n=0;n<2;n++){ qr[m][n] = (f32x4){0,0,0,0}; qi[m][n] = (f32x4){0,0,0,0}; }
  #pragma unroll
  for (int kk = 0; kk < 4; kk++){
    int kb = kk*32 + hi*8;
    #pragma unroll
    for (int m=0;m<4;m++){
      int r = wr + m*16 + l15;
      int o = swz16(r, kb*2);
      s16x8 a_r = *(const s16x8*)(T1r + o);
      s16x8 a_i = *(const s16x8*)(T1i + o);
      #pragma unroll
      for (int n=0;n<2;n++){
        int c = wc + n*16 + l15;
        s16x8 b_r = *(const s16x8*)(w.rootR + c*128 + kb);
        s16x8 b_i = *(const s16x8*)(w.rootI + c*128 + kb);
        cmfma<0,1>(a_r, a_i, b_r, b_i, qr[m][n], qi[m][n]);
      }
    }
  }
  __syncthreads();
  double* red = (double*)T1r;
  const u16* rlr = w.rho + (size_t)2*MATN;
  const u16* rli = rlr + MATN;
  double a1 = 0.0;
  #pragma unroll
  for (int m=0;m<4;m++)
    #pragma unroll
    for (int n=0;n<2;n++){
      int c = wc + n*16 + l15, r0 = wr + m*16 + hi*4;
      #pragma unroll
      for (int q=0;q<4;q++){
        int r = r0 + q;
        float lr = bf2f(rlr[r*128 + c]), li = bf2f(rli[r*128 + c]);
        a1 += (double)qr[m][n][q]*lr - (double)qi[m][n][q]*li;
      }
    }
  red[t] = a1; __syncthreads();
  for (int o = 256; o > 0; o >>= 1){ if (t < o) red[t] += red[t+o]; __syncthreads(); }
  double that = red[0]; __syncthreads();
  const u16* rrr = w.rho;
  const u16* rri = rrr + MATN;
  double a2 = 0.0;
  for (int idx = t; idx < MATN; idx += 512){
    int c = idx >> 7, r = idx & 127;
    float ar_ = bf2f(rrr[idx]), ai_ = bf2f(rri[idx]);
    float lr  = bf2f(rlr[r*128 + c]), li = bf2f(rli[r*128 + c]);
    a2 += (double)ar_*lr - (double)ai_*li;
  }
  red[t] = a2; __syncthreads();
  for (int o = 256; o > 0; o >>= 1){ if (t < o) red[t] += red[t+o]; __syncthreads(); }
  double trrl = red[0];
  if (t == 0){
    double T0 = 0.0, T1s = 0.0;
    for (int s = 0; s < 8; s++){ T0 += w.trbuf[8+s]; T1s += w.trbuf[16+8+s]; }
    double lam = ldexp(T1s / T0, S1SH + S2SH);
    double logp = (double)LSEQ * log2(lam) - 2.0*(double)w.Eroot[0] - (double)CHSH
                  - log2(fmax(that, 1e-300)) + log2(fmax(trrl, 1e-300));
    w.out[0] = (float)logp;
  }
}

// ----------------- host -----------------
static inline size_t aln256(size_t x){ return (x + 255) & ~(size_t)255; }

extern "C" void kernel_launch(void* const* d_in, const int* in_sizes, int n_in,
                              void* d_out, int out_size, void* d_ws, size_t ws_size,
                              hipStream_t stream){
  const float* Kre = (const float*)d_in[0];
  const float* Kim = (const float*)d_in[1];
  const int*   seq = (const int*)d_in[2];

  WS w{};
  char* p = (char*)d_ws;
  auto take = [&](size_t bytes)->char*{ char* r = p; p += aln256(bytes); return r; };
  w.Kb    = (u16*)take((size_t)NA*4*MATN*2);
  w.P2b   = (u16*)take((size_t)64*4*MATN*2);
  w.rho   = (u16*)take((size_t)8*MATN*2);
  w.nodes0= (u16*)take((size_t)GCH*2*MATN*2);
  w.nodes1= (u16*)take((size_t)(GCH/4)*2*MATN*2);
  w.tok   = (int*)take(NTOK*4);
  w.E0    = (int*)take(GCH*4);
  w.E1    = (int*)take(GCH*4);
  w.trbuf = (float*)take(32*4);
  w.out = (float*)d_out;
  // levels: 256 ->64(n0->n1) ->16(n1->n0) ->4(n0->n1) ->1(n1->n0, root)
  w.rootR = w.nodes0; w.rootI = w.nodes0 + MATN;
  w.Eroot = w.E0;

  hipLaunchKernelGGL(k_kbinit, dim3(NA*16), dim3(256), 0, stream, Kre, Kim, seq, w);
  hipLaunchKernelGGL(k_p2, dim3(64*16), dim3(256), 0, stream, Kre, Kim, w);
  hipLaunchKernelGGL(k_chain, dim3(GCH), dim3(512), 0, stream, w);
  hipLaunchKernelGGL(k_level, dim3(64), dim3(512), 0, stream, w, 1, 0);
  hipLaunchKernelGGL(k_level, dim3(16), dim3(512), 0, stream, w, 0, 0);
  hipLaunchKernelGGL(k_level, dim3(4),  dim3(512), 0, stream, w, 1, 0);
  hipLaunchKernelGGL(k_level, dim3(1),  dim3(512), 0, stream, w, 0, 1);
  for (int k = 0; k < PITERS; k++)
    hipLaunchKernelGGL(k_pow, dim3(16), dim3(512), 0, stream, w, k & 1);
  hipLaunchKernelGGL(k_epi, dim3(1), dim3(512), 0, stream, w);
}

// Round 11
// 309.986 us; speedup vs baseline: 1.1222x; 1.1222x over previous
//
#include <hip/hip_runtime.h>

typedef unsigned int u32;
typedef unsigned short u16;
typedef __attribute__((ext_vector_type(4))) float f32x4;
typedef __attribute__((ext_vector_type(8))) short s16x8;
typedef __attribute__((ext_vector_type(4))) u32 u32x4;

#define DIMN 128
#define MATN (DIMN*DIMN)
#define NA 8
#define LSEQ 8192
#define NTOK (LSEQ/2)
#define PITERS 4
#define S1SH 5
#define S2SH 6
#define CHSH 7
#define P2SH 8
#define GCH 256
#define GLG 16

struct WS {
  u16 *Kb, *P2b, *rho, *nodes0, *nodes1, *rootR, *rootI;
  int *tok, *E0, *E1, *Eroot;
  float *trbuf;
  float *out;
};

__device__ __forceinline__ u16 f2bf(float x){
  u32 u = __float_as_uint(x);
  u32 r = (u + 0x7FFFu + ((u >> 16) & 1u)) >> 16;
  return (u16)r;
}
__device__ __forceinline__ float bf2f(u16 u){ return __uint_as_float(((u32)u) << 16); }
__device__ __forceinline__ u32 cvtpk(float lo, float hi){
  u32 r; asm("v_cvt_pk_bf16_f32 %0, %1, %2" : "=v"(r) : "v"(lo), "v"(hi)); return r;
}
__device__ __forceinline__ s16x8 negi(s16x8 v){
  return __builtin_bit_cast(s16x8, __builtin_bit_cast(u32x4, v) ^ 0x80008000u);
}
__device__ __forceinline__ int swz16(int maj, int b){
  return maj*256 + (((((b >> 4) + maj*5) & 15) << 4) | (b & 15));
}
template<int CA, int CB>
__device__ __forceinline__ void cmfma(s16x8 a_r, s16x8 a_i, s16x8 b_r, s16x8 b_i,
                                      f32x4& qr, f32x4& qi){
  s16x8 t1 = (CA ^ CB) ? a_i : negi(a_i);
  s16x8 t2 = CB ? negi(a_r) : a_r;
  s16x8 t3 = CA ? negi(a_i) : a_i;
  qr = __builtin_amdgcn_mfma_f32_16x16x32_bf16(a_r, b_r, qr, 0,0,0);
  qr = __builtin_amdgcn_mfma_f32_16x16x32_bf16(t1,  b_i, qr, 0,0,0);
  qi = __builtin_amdgcn_mfma_f32_16x16x32_bf16(t2,  b_i, qi, 0,0,0);
  qi = __builtin_amdgcn_mfma_f32_16x16x32_bf16(t3,  b_r, qi, 0,0,0);
}

// ----------------- k_kbinit: Kb bf16 planes + tokens + rho + trbuf ----------
__global__ __launch_bounds__(256) void k_kbinit(const float* Kre, const float* Kim,
                                                const int* seq, WS w){
  __shared__ u16 Lr[32][36], Li[32][36];
  int blk = blockIdx.x, x = blk >> 4, tile = blk & 15;
  int row0 = (tile>>2)*32, col0 = (tile&3)*32;
  int t = threadIdx.x;
  { int r = t>>3, cch = t&7;
    size_t off = (size_t)x*MATN + (size_t)(row0+r)*128 + col0 + cch*4;
    float4 vr = *(const float4*)(Kre + off);
    float4 vi = *(const float4*)(Kim + off);
    Lr[r][cch*4+0] = f2bf(vr.x); Lr[r][cch*4+1] = f2bf(vr.y);
    Lr[r][cch*4+2] = f2bf(vr.z); Lr[r][cch*4+3] = f2bf(vr.w);
    Li[r][cch*4+0] = f2bf(vi.x); Li[r][cch*4+1] = f2bf(vi.y);
    Li[r][cch*4+2] = f2bf(vi.z); Li[r][cch*4+3] = f2bf(vi.w);
  }
  __syncthreads();
  u16* b = w.Kb + (size_t)x*4*MATN;
  { int r = t>>3, cch = t&7;
    *(uint2*)&b[(row0+r)*128 + col0 + cch*4]        = *(uint2*)&Lr[r][cch*4];
    *(uint2*)&b[MATN + (row0+r)*128 + col0 + cch*4] = *(uint2*)&Li[r][cch*4];
  }
  { int c = t>>3, rch = t&7;
    ushort4 vr, vi;
    vr.x = Lr[rch*4+0][c]; vr.y = Lr[rch*4+1][c];
    vr.z = Lr[rch*4+2][c]; vr.w = Lr[rch*4+3][c];
    vi.x = Li[rch*4+0][c]; vi.y = Li[rch*4+1][c];
    vi.z = Li[rch*4+2][c]; vi.w = Li[rch*4+3][c];
    *(ushort4*)&b[2*MATN + (col0+c)*128 + row0 + rch*4] = vr;
    *(ushort4*)&b[3*MATN + (col0+c)*128 + row0 + rch*4] = vi;
  }
  int gid = blockIdx.x*256 + t, gsz = gridDim.x*256;
  for (int i = gid; i < NTOK; i += gsz)
    w.tok[i] = seq[2*i+1]*NA + seq[2*i];
  for (int i = gid; i < 4*MATN; i += gsz){
    int plane = (i >> 14) & 1, rem = i & (MATN-1);
    u16 v = (plane == 0 && (rem >> 7) == (rem & 127)) ? f2bf(1.f) : (u16)0;
    w.rho[i] = v;
  }
  if (gid < 32) w.trbuf[gid] = 0.f;
}

// ------- shared MFMA machinery: 8 waves, 4 row-groups x 2 col-groups -------
__device__ __forceinline__ void ccompute(const u16* Ar, const u16* Ai,
    const char* Pr, const char* Pi, f32x4 (&qr)[2][4], f32x4 (&qi)[2][4], int t){
  int wv = t>>6, lane = t&63, l15 = lane&15, hi = lane>>4;
  int wr = (wv>>1)*32, wc = (wv&1)*64;
  #pragma unroll
  for (int m=0;m<2;m++)
    #pragma unroll
    for (int n=0;n<4;n++){ qr[m][n] = (f32x4){0,0,0,0}; qi[m][n] = (f32x4){0,0,0,0}; }
  #pragma unroll
  for (int kk = 0; kk < 4; kk++){
    int kb = kk*32 + hi*8;
    s16x8 a_r[2], a_i[2];
    #pragma unroll
    for (int m=0;m<2;m++){
      int r = wr + m*16 + l15;
      a_r[m] = *(const s16x8*)(Ar + r*128 + kb);
      a_i[m] = *(const s16x8*)(Ai + r*128 + kb);
    }
    #pragma unroll
    for (int n=0;n<4;n++){
      int c = wc + n*16 + l15;
      int o = swz16(c, kb*2);
      s16x8 b_r = *(const s16x8*)(Pr + o);
      s16x8 b_i = *(const s16x8*)(Pi + o);
      #pragma unroll
      for (int m=0;m<2;m++)
        cmfma<0,0>(a_r[m], a_i[m], b_r, b_i, qr[m][n], qi[m][n]);
    }
  }
}
__device__ __forceinline__ void pwrite16(char* Pr, char* Pi,
    f32x4 (&qr)[2][4], f32x4 (&qi)[2][4], float sc, int t){
  int wv = t>>6, lane = t&63, l15 = lane&15, hi = lane>>4;
  int wr = (wv>>1)*32, wc = (wv&1)*64;
  #pragma unroll
  for (int m=0;m<2;m++)
    #pragma unroll
    for (int n=0;n<4;n++){
      int c = wc + n*16 + l15, r0 = wr + m*16 + hi*4;
      uint2 pr, pi;
      pr.x = cvtpk(qr[m][n][0]*sc, qr[m][n][1]*sc);
      pr.y = cvtpk(qr[m][n][2]*sc, qr[m][n][3]*sc);
      pi.x = cvtpk(qi[m][n][0]*sc, qi[m][n][1]*sc);
      pi.y = cvtpk(qi[m][n][2]*sc, qi[m][n][3]*sc);
      int o = swz16(c, r0*2);
      *(uint2*)(Pr + o) = pr;
      *(uint2*)(Pi + o) = pi;
    }
}
// max-renorm into DEST buffers (dbuf-safe); one internal barrier
__device__ __forceinline__ int renorm_to(char* Pr, char* Pi, float* red,
    f32x4 (&qr)[2][4], f32x4 (&qi)[2][4], int t){
  int wv = t>>6, lane = t&63;
  float lm = 0.f;
  #pragma unroll
  for (int m=0;m<2;m++)
    #pragma unroll
    for (int n=0;n<4;n++)
      #pragma unroll
      for (int j=0;j<4;j++)
        lm = fmaxf(lm, fmaxf(fabsf(qr[m][n][j]), fabsf(qi[m][n][j])));
  #pragma unroll
  for (int o = 32; o > 0; o >>= 1) lm = fmaxf(lm, __shfl_xor(lm, o, 64));
  if (lane == 0) red[wv] = lm;
  __syncthreads();
  float mx = 0.f;
  #pragma unroll
  for (int i = 0; i < 8; i++) mx = fmaxf(mx, red[i]);
  int e = 0; if (mx > 0.f) frexpf(mx, &e);
  pwrite16(Pr, Pi, qr, qi, ldexpf(1.f, -e), t);
  return e;
}
__device__ __forceinline__ void stage_cols16(const u16* gr, const u16* gi,
                                             char* Pr, char* Pi, int t){
  #pragma unroll
  for (int i = 0; i < 4; i++){
    int chunk = t + i*512;
    int c = chunk >> 4, rr = chunk & 15;
    int o = swz16(c, rr*16);
    *(uint4*)(Pr + o) = *(const uint4*)(gr + c*128 + rr*8);
    *(uint4*)(Pi + o) = *(const uint4*)(gi + c*128 + rr*8);
  }
}
__device__ __forceinline__ void write_node16(u16* dr, u16* di,
    const char* Pr, const char* Pi, bool rowLayout, int t){
  if (!rowLayout){
    #pragma unroll
    for (int i = 0; i < 4; i++){
      int chunk = t + i*512;
      int c = chunk >> 4, rr = chunk & 15;
      int o = swz16(c, rr*16);
      *(uint4*)(dr + c*128 + rr*8) = *(const uint4*)(Pr + o);
      *(uint4*)(di + c*128 + rr*8) = *(const uint4*)(Pi + o);
    }
  } else {
    for (int idx = t; idx < MATN; idx += 512){
      int r = idx >> 7, c = idx & 127;
      int o = swz16(c, r*2);
      dr[idx] = *(const u16*)(Pr + o);
      di[idx] = *(const u16*)(Pi + o);
    }
  }
}

// ----------------- k_p2m: P2 = Ka @ Kb via bf16 MFMA -> bf16 planes ---------
__global__ __launch_bounds__(512) void k_p2m(WS w){
  __shared__ __align__(16) char P0r[32768];
  __shared__ __align__(16) char P0i[32768];
  __shared__ __align__(16) char P1r[32768];
  __shared__ __align__(16) char P1i[32768];
  int blk = blockIdx.x, a = blk >> 3, b = blk & 7;
  int t = threadIdx.x;
  const u16* Bb = w.Kb + (size_t)(b*4 + 2)*MATN;   // col planes of Kb[b]
  stage_cols16(Bb, Bb + MATN, P0r, P0i, t);
  __syncthreads();
  const u16* Ab = w.Kb + (size_t)(a*4)*MATN;        // row planes of Kb[a]
  f32x4 qr[2][4], qi[2][4];
  ccompute(Ab, Ab + MATN, P0r, P0i, qr, qi, t);
  pwrite16(P1r, P1i, qr, qi, 1.f/(1<<P2SH), t);
  __syncthreads();
  u16* base = w.P2b + (size_t)blk*4*MATN;
  write_node16(base + 2*MATN, base + 3*MATN, P1r, P1i, false, t);  // col planes
  write_node16(base, base + MATN, P1r, P1i, true, t);              // row planes
}

// chains: 256 blocks, 15 products; LDS dbuf, ONE barrier per step ------------
__global__ __launch_bounds__(512,2) void k_chain(WS w){
  __shared__ __align__(16) char P0r[32768];
  __shared__ __align__(16) char P0i[32768];
  __shared__ __align__(16) char P1r[32768];
  __shared__ __align__(16) char P1i[32768];
  __shared__ float red[8];
  int p = blockIdx.x, t = threadIdx.x;
  char *PrC = P0r, *PiC = P0i, *PrN = P1r, *PiN = P1i;
  int tok0 = w.tok[p*GLG];
  const u16* b0 = w.P2b + (size_t)tok0*4*MATN;
  stage_cols16(b0 + 2*MATN, b0 + 3*MATN, PrC, PiC, t);
  f32x4 qr[2][4], qi[2][4];
  int eLast = 0;
  __syncthreads();
  #pragma unroll 1
  for (int s = 1; s < GLG; s++){
    const u16* tb = w.P2b + (size_t)w.tok[p*GLG + s]*4*MATN;
    ccompute(tb, tb + MATN, PrC, PiC, qr, qi, t);
    if (s < GLG-1) pwrite16(PrN, PiN, qr, qi, 1.f/(1<<CHSH), t);
    else eLast = renorm_to(PrN, PiN, red, qr, qi, t);
    __syncthreads();
    { char* x = PrC; PrC = PrN; PrN = x; x = PiC; PiC = PiN; PiN = x; }
  }
  u16* slot = w.nodes0 + (size_t)p*2*MATN;
  write_node16(slot, slot + MATN, PrC, PiC, (p & 3) != 0, t);
  if (t == 0) w.E0[p] = P2SH*GLG + CHSH*(GLG-2) + eLast;
}

// radix-4 level: dbuf, one barrier per product --------------------------------
__global__ __launch_bounds__(512,2) void k_level(WS w, int srcIs0, int isRoot){
  __shared__ __align__(16) char P0r[32768];
  __shared__ __align__(16) char P0i[32768];
  __shared__ __align__(16) char P1r[32768];
  __shared__ __align__(16) char P1i[32768];
  __shared__ float red[8];
  int p = blockIdx.x, t = threadIdx.x;
  char *PrC = P0r, *PiC = P0i, *PrN = P1r, *PiN = P1i;
  const u16* src = srcIs0 ? w.nodes0 : w.nodes1;
  u16* dst       = srcIs0 ? w.nodes1 : w.nodes0;
  const int* Es  = srcIs0 ? w.E0 : w.E1;
  int* Ed        = srcIs0 ? w.E1 : w.E0;
  const u16* B = src + (size_t)(4*p)*2*MATN;
  stage_cols16(B, B + MATN, PrC, PiC, t);
  int E = Es[4*p] + Es[4*p+1] + Es[4*p+2] + Es[4*p+3];
  f32x4 qr[2][4], qi[2][4];
  __syncthreads();
  #pragma unroll 1
  for (int j = 1; j < 4; j++){
    const u16* A = src + (size_t)(4*p + j)*2*MATN;
    ccompute(A, A + MATN, PrC, PiC, qr, qi, t);
    E += renorm_to(PrN, PiN, red, qr, qi, t);
    __syncthreads();
    { char* x = PrC; PrC = PrN; PrN = x; x = PiC; PiC = PiN; PiN = x; }
  }
  u16* slot = dst + (size_t)p*2*MATN;
  write_node16(slot, slot + MATN, PrC, PiC, ((p & 3) != 0) || isRoot, t);
  if (t == 0) Ed[p] = E;
}

// -------- fused power iteration (R8 verbatim) --------
__global__ __launch_bounds__(512,1) void k_pow(WS w, int par){
  __shared__ __align__(16) char Rr[32768];
  __shared__ __align__(16) char Ri[32768];
  __shared__ __align__(16) char Yr[32768];
  __shared__ __align__(16) char Yi[32768];
  int b = blockIdx.x, side = b >> 3, rb = b & 7;
  int t = threadIdx.x, wv = t>>6, lane = t&63, l15 = lane&15, hi = lane>>4;
  const u16* rhoS = w.rho + (size_t)((par*2 + side)*2)*MATN;
  stage_cols16(rhoS, rhoS + MATN, Rr, Ri, t);
  __syncthreads();
  { int x = wv;
    const u16* Ab = w.Kb + (size_t)(x*4 + (side ? 2 : 0))*MATN;
    const u16* Ar = Ab; const u16* Ai = Ab + MATN;
    f32x4 q1r[8], q1i[8];
    #pragma unroll
    for (int n=0;n<8;n++){ q1r[n] = (f32x4){0,0,0,0}; q1i[n] = (f32x4){0,0,0,0}; }
    #pragma unroll
    for (int kk = 0; kk < 4; kk++){
      int kb = kk*32 + hi*8;
      int r = rb*16 + l15;
      s16x8 a_r = *(const s16x8*)(Ar + r*128 + kb);
      s16x8 a_i = *(const s16x8*)(Ai + r*128 + kb);
      #pragma unroll
      for (int n=0;n<8;n++){
        int c = n*16 + l15;
        int o = swz16(c, kb*2);
        s16x8 b_r = *(const s16x8*)(Rr + o);
        s16x8 b_i = *(const s16x8*)(Ri + o);
        if (side == 0) cmfma<0,0>(a_r, a_i, b_r, b_i, q1r[n], q1i[n]);
        else           cmfma<1,0>(a_r, a_i, b_r, b_i, q1r[n], q1i[n]);
      }
    }
    const float sc = 1.f/(1<<S1SH);
    #pragma unroll
    for (int n=0;n<8;n++)
      #pragma unroll
      for (int q=0;q<4;q++){
        int lr = hi*4 + q, c = n*16 + l15;
        *(u16*)(Yr + x*4096 + swz16(lr, c*2)) = f2bf(q1r[n][q]*sc);
        *(u16*)(Yi + x*4096 + swz16(lr, c*2)) = f2bf(q1i[n][q]*sc);
      }
  }
  __syncthreads();
  { int c0 = wv*16, c = c0 + l15;
    f32x4 q2r = {0,0,0,0}, q2i = {0,0,0,0};
    #pragma unroll 2
    for (int x = 0; x < 8; x++){
      const u16* Bb = w.Kb + (size_t)(x*4 + (side ? 2 : 0))*MATN;
      const u16* Br = Bb; const u16* Bi = Bb + MATN;
      #pragma unroll
      for (int kk = 0; kk < 4; kk++){
        int kb = kk*32 + hi*8;
        s16x8 a_r = *(const s16x8*)(Yr + x*4096 + swz16(l15, kb*2));
        s16x8 a_i = *(const s16x8*)(Yi + x*4096 + swz16(l15, kb*2));
        s16x8 b_r = *(const s16x8*)(Br + c*128 + kb);
        s16x8 b_i = *(const s16x8*)(Bi + c*128 + kb);
        if (side == 0) cmfma<0,1>(a_r, a_i, b_r, b_i, q2r, q2i);
        else           cmfma<0,0>(a_r, a_i, b_r, b_i, q2r, q2i);
      }
    }
    const float sc = 1.f/(1<<S2SH);
    u16* Dr = w.rho + (size_t)(((par^1)*2 + side)*2)*MATN;
    u16* Di = Dr + MATN;
    int r0g = rb*16 + hi*4;
    uint2 pr, pi;
    pr.x = cvtpk(q2r[0]*sc, q2r[1]*sc); pr.y = cvtpk(q2r[2]*sc, q2r[3]*sc);
    pi.x = cvtpk(q2i[0]*sc, q2i[1]*sc); pi.y = cvtpk(q2i[2]*sc, q2i[3]*sc);
    *(uint2*)(Dr + c*128 + r0g) = pr;
    *(uint2*)(Di + c*128 + r0g) = pi;
    if (side == 1 && wv == rb){
      float tr = 0.f;
      #pragma unroll
      for (int q=0;q<4;q++) if (hi*4 + q == l15) tr += q2r[q]*sc;
      #pragma unroll
      for (int o = 32; o > 0; o >>= 1) tr += __shfl_xor(tr, o, 64);
      if (lane == 0) w.trbuf[par*16 + 8 + rb] = tr;
    }
  }
}

// ----------------- fused epilogue (R8 verbatim) -----------------
__global__ __launch_bounds__(512) void k_epi(WS w){
  __shared__ __align__(16) char T1r[32768];
  __shared__ __align__(16) char T1i[32768];
  int t = threadIdx.x, wv = t>>6, lane = t&63, l15 = lane&15, hi = lane>>4;
  int wr = (wv>>2)*64, wc = (wv&3)*32;
  f32x4 qr[4][2], qi[4][2];
  const u16* Ar = w.rho;
  const u16* Ai = Ar + MATN;
  #pragma unroll
  for (int m=0;m<4;m++)
    #pragma unroll
    for (int n=0;n<2;n++){ qr[m][n] = (f32x4){0,0,0,0}; qi[m][n] = (f32x4){0,0,0,0}; }
  #pragma unroll
  for (int kk = 0; kk < 4; kk++){
    int kb = kk*32 + hi*8;
    #pragma unroll
    for (int m=0;m<4;m++){
      int r = wr + m*16 + l15;
      s16x8 a_r = *(const s16x8*)(Ar + r*128 + kb);
      s16x8 a_i = *(const s16x8*)(Ai + r*128 + kb);
      #pragma unroll
      for (int n=0;n<2;n++){
        int c = wc + n*16 + l15;
        s16x8 b_r = *(const s16x8*)(w.rootR + c*128 + kb);
        s16x8 b_i = *(const s16x8*)(w.rootI + c*128 + kb);
        cmfma<0,0>(a_r, a_i, b_r, b_i, qr[m][n], qi[m][n]);
      }
    }
  }
  {
    const float sc = 1.f/(1<<CHSH);
    #pragma unroll
    for (int m=0;m<4;m++)
      #pragma unroll
      for (int n=0;n<2;n++){
        int c = wc + n*16 + l15, r0 = wr + m*16 + hi*4;
        uint2 pr, pi;
        pr.x = cvtpk(qr[m][n][0]*sc, qr[m][n][1]*sc);
        pr.y = cvtpk(qr[m][n][2]*sc, qr[m][n][3]*sc);
        pi.x = cvtpk(qi[m][n][0]*sc, qi[m][n][1]*sc);
        pi.y = cvtpk(qi[m][n][2]*sc, qi[m][n][3]*sc);
        int o = swz16(c, r0*2);
        *(uint2*)(T1r + o) = pr;
        *(uint2*)(T1i + o) = pi;
      }
  }
  __syncthreads();
  #pragma unroll
  for (int m=0;m<4;m++)
    #pragma unroll
    for (int n=0;n<2;n++){ qr[m][n] = (f32x4){0,0,0,0}; qi[m][n] = (f32x4){0,0,0,0}; }
  #pragma unroll
  for (int kk = 0; kk < 4; kk++){
    int kb = kk*32 + hi*8;
    #pragma unroll
    for (int m=0;m<4;m++){
      int r = wr + m*16 + l15;
      int o = swz16(r, kb*2);
      s16x8 a_r = *(const s16x8*)(T1r + o);
      s16x8 a_i = *(const s16x8*)(T1i + o);
      #pragma unroll
      for (int n=0;n<2;n++){
        int c = wc + n*16 + l15;
        s16x8 b_r = *(const s16x8*)(w.rootR + c*128 + kb);
        s16x8 b_i = *(const s16x8*)(w.rootI + c*128 + kb);
        cmfma<0,1>(a_r, a_i, b_r, b_i, qr[m][n], qi[m][n]);
      }
    }
  }
  __syncthreads();
  double* red = (double*)T1r;
  const u16* rlr = w.rho + (size_t)2*MATN;
  const u16* rli = rlr + MATN;
  double a1 = 0.0;
  #pragma unroll
  for (int m=0;m<4;m++)
    #pragma unroll
    for (int n=0;n<2;n++){
      int c = wc + n*16 + l15, r0 = wr + m*16 + hi*4;
      #pragma unroll
      for (int q=0;q<4;q++){
        int r = r0 + q;
        float lr = bf2f(rlr[r*128 + c]), li = bf2f(rli[r*128 + c]);
        a1 += (double)qr[m][n][q]*lr - (double)qi[m][n][q]*li;
      }
    }
  red[t] = a1; __syncthreads();
  for (int o = 256; o > 0; o >>= 1){ if (t < o) red[t] += red[t+o]; __syncthreads(); }
  double that = red[0]; __syncthreads();
  const u16* rrr = w.rho;
  const u16* rri = rrr + MATN;
  double a2 = 0.0;
  for (int idx = t; idx < MATN; idx += 512){
    int c = idx >> 7, r = idx & 127;
    float ar_ = bf2f(rrr[idx]), ai_ = bf2f(rri[idx]);
    float lr  = bf2f(rlr[r*128 + c]), li = bf2f(rli[r*128 + c]);
    a2 += (double)ar_*lr - (double)ai_*li;
  }
  red[t] = a2; __syncthreads();
  for (int o = 256; o > 0; o >>= 1){ if (t < o) red[t] += red[t+o]; __syncthreads(); }
  double trrl = red[0];
  if (t == 0){
    double T0 = 0.0, T1s = 0.0;
    for (int s = 0; s < 8; s++){ T0 += w.trbuf[8+s]; T1s += w.trbuf[16+8+s]; }
    double lam = ldexp(T1s / T0, S1SH + S2SH);
    double logp = (double)LSEQ * log2(lam) - 2.0*(double)w.Eroot[0] - (double)CHSH
                  - log2(fmax(that, 1e-300)) + log2(fmax(trrl, 1e-300));
    w.out[0] = (float)logp;
  }
}

// ----------------- host -----------------
static inline size_t aln256(size_t x){ return (x + 255) & ~(size_t)255; }

extern "C" void kernel_launch(void* const* d_in, const int* in_sizes, int n_in,
                              void* d_out, int out_size, void* d_ws, size_t ws_size,
                              hipStream_t stream){
  const float* Kre = (const float*)d_in[0];
  const float* Kim = (const float*)d_in[1];
  const int*   seq = (const int*)d_in[2];

  WS w{};
  char* p = (char*)d_ws;
  auto take = [&](size_t bytes)->char*{ char* r = p; p += aln256(bytes); return r; };
  w.Kb    = (u16*)take((size_t)NA*4*MATN*2);
  w.P2b   = (u16*)take((size_t)64*4*MATN*2);
  w.rho   = (u16*)take((size_t)8*MATN*2);
  w.nodes0= (u16*)take((size_t)GCH*2*MATN*2);
  w.nodes1= (u16*)take((size_t)(GCH/4)*2*MATN*2);
  w.tok   = (int*)take(NTOK*4);
  w.E0    = (int*)take(GCH*4);
  w.E1    = (int*)take(GCH*4);
  w.trbuf = (float*)take(32*4);
  w.out = (float*)d_out;
  // levels: 256 ->64(n0->n1) ->16(n1->n0) ->4(n0->n1) ->1(n1->n0, root)
  w.rootR = w.nodes0; w.rootI = w.nodes0 + MATN;
  w.Eroot = w.E0;

  hipLaunchKernelGGL(k_kbinit, dim3(NA*16), dim3(256), 0, stream, Kre, Kim, seq, w);
  hipLaunchKernelGGL(k_p2m, dim3(64), dim3(512), 0, stream, w);
  hipLaunchKernelGGL(k_chain, dim3(GCH), dim3(512), 0, stream, w);
  hipLaunchKernelGGL(k_level, dim3(64), dim3(512), 0, stream, w, 1, 0);
  hipLaunchKernelGGL(k_level, dim3(16), dim3(512), 0, stream, w, 0, 0);
  hipLaunchKernelGGL(k_level, dim3(4),  dim3(512), 0, stream, w, 1, 0);
  hipLaunchKernelGGL(k_level, dim3(1),  dim3(512), 0, stream, w, 0, 1);
  for (int k = 0; k < PITERS; k++)
    hipLaunchKernelGGL(k_pow, dim3(16), dim3(512), 0, stream, w, k & 1);
  hipLaunchKernelGGL(k_epi, dim3(1), dim3(512), 0, stream, w);
}

// Round 12
// 305.920 us; speedup vs baseline: 1.1371x; 1.0133x over previous
//
#include <hip/hip_runtime.h>

typedef unsigned int u32;
typedef unsigned short u16;
typedef __attribute__((ext_vector_type(4))) float f32x4;
typedef __attribute__((ext_vector_type(8))) short s16x8;
typedef __attribute__((ext_vector_type(4))) u32 u32x4;

#define DIMN 128
#define MATN (DIMN*DIMN)
#define NA 8
#define LSEQ 8192
#define NTOK (LSEQ/2)
#define PITERS 4
#define S1SH 5
#define S2SH 6
#define CHSH 7
#define P2SH 8
#define GCH 256
#define GLG 16

struct WS {
  u16 *Kb, *P2b, *rho, *nodes0, *nodes1, *rootR, *rootI;
  int *tok, *E0, *E1, *Eroot;
  float *trbuf;
  float *out;
};

__device__ __forceinline__ u16 f2bf(float x){
  u32 u = __float_as_uint(x);
  u32 r = (u + 0x7FFFu + ((u >> 16) & 1u)) >> 16;
  return (u16)r;
}
__device__ __forceinline__ float bf2f(u16 u){ return __uint_as_float(((u32)u) << 16); }
__device__ __forceinline__ u32 cvtpk(float lo, float hi){
  u32 r; asm("v_cvt_pk_bf16_f32 %0, %1, %2" : "=v"(r) : "v"(lo), "v"(hi)); return r;
}
__device__ __forceinline__ s16x8 negi(s16x8 v){
  return __builtin_bit_cast(s16x8, __builtin_bit_cast(u32x4, v) ^ 0x80008000u);
}
__device__ __forceinline__ int swz16(int maj, int b){
  return maj*256 + (((((b >> 4) + maj*5) & 15) << 4) | (b & 15));
}
template<int CA, int CB>
__device__ __forceinline__ void cmfma(s16x8 a_r, s16x8 a_i, s16x8 b_r, s16x8 b_i,
                                      f32x4& qr, f32x4& qi){
  s16x8 t1 = (CA ^ CB) ? a_i : negi(a_i);
  s16x8 t2 = CB ? negi(a_r) : a_r;
  s16x8 t3 = CA ? negi(a_i) : a_i;
  qr = __builtin_amdgcn_mfma_f32_16x16x32_bf16(a_r, b_r, qr, 0,0,0);
  qr = __builtin_amdgcn_mfma_f32_16x16x32_bf16(t1,  b_i, qr, 0,0,0);
  qi = __builtin_amdgcn_mfma_f32_16x16x32_bf16(t2,  b_i, qi, 0,0,0);
  qi = __builtin_amdgcn_mfma_f32_16x16x32_bf16(t3,  b_r, qi, 0,0,0);
}

// ----------------- k_kbinit: Kb bf16 planes + tokens + rho + trbuf ----------
__global__ __launch_bounds__(256) void k_kbinit(const float* Kre, const float* Kim,
                                                const int* seq, WS w){
  __shared__ u16 Lr[32][36], Li[32][36];
  int blk = blockIdx.x, x = blk >> 4, tile = blk & 15;
  int row0 = (tile>>2)*32, col0 = (tile&3)*32;
  int t = threadIdx.x;
  { int r = t>>3, cch = t&7;
    size_t off = (size_t)x*MATN + (size_t)(row0+r)*128 + col0 + cch*4;
    float4 vr = *(const float4*)(Kre + off);
    float4 vi = *(const float4*)(Kim + off);
    Lr[r][cch*4+0] = f2bf(vr.x); Lr[r][cch*4+1] = f2bf(vr.y);
    Lr[r][cch*4+2] = f2bf(vr.z); Lr[r][cch*4+3] = f2bf(vr.w);
    Li[r][cch*4+0] = f2bf(vi.x); Li[r][cch*4+1] = f2bf(vi.y);
    Li[r][cch*4+2] = f2bf(vi.z); Li[r][cch*4+3] = f2bf(vi.w);
  }
  __syncthreads();
  u16* b = w.Kb + (size_t)x*4*MATN;
  { int r = t>>3, cch = t&7;
    *(uint2*)&b[(row0+r)*128 + col0 + cch*4]        = *(uint2*)&Lr[r][cch*4];
    *(uint2*)&b[MATN + (row0+r)*128 + col0 + cch*4] = *(uint2*)&Li[r][cch*4];
  }
  { int c = t>>3, rch = t&7;
    ushort4 vr, vi;
    vr.x = Lr[rch*4+0][c]; vr.y = Lr[rch*4+1][c];
    vr.z = Lr[rch*4+2][c]; vr.w = Lr[rch*4+3][c];
    vi.x = Li[rch*4+0][c]; vi.y = Li[rch*4+1][c];
    vi.z = Li[rch*4+2][c]; vi.w = Li[rch*4+3][c];
    *(ushort4*)&b[2*MATN + (col0+c)*128 + row0 + rch*4] = vr;
    *(ushort4*)&b[3*MATN + (col0+c)*128 + row0 + rch*4] = vi;
  }
  int gid = blockIdx.x*256 + t, gsz = gridDim.x*256;
  for (int i = gid; i < NTOK; i += gsz)
    w.tok[i] = seq[2*i+1]*NA + seq[2*i];
  for (int i = gid; i < 4*MATN; i += gsz){
    int plane = (i >> 14) & 1, rem = i & (MATN-1);
    u16 v = (plane == 0 && (rem >> 7) == (rem & 127)) ? f2bf(1.f) : (u16)0;
    w.rho[i] = v;
  }
  if (gid < 32) w.trbuf[gid] = 0.f;
}

// ------- shared MFMA machinery: 8 waves, 4 row-groups x 2 col-groups -------
__device__ __forceinline__ void loadA(const u16* Ar, const u16* Ai,
    int wr, int l15, int hi, s16x8 (&fr)[4][2], s16x8 (&fi)[4][2]){
  #pragma unroll
  for (int kk = 0; kk < 4; kk++){
    int kb = kk*32 + hi*8;
    #pragma unroll
    for (int m = 0; m < 2; m++){
      int r = wr + m*16 + l15;
      fr[kk][m] = *(const s16x8*)(Ar + r*128 + kb);
      fi[kk][m] = *(const s16x8*)(Ai + r*128 + kb);
    }
  }
}
__device__ __forceinline__ void ccomputeR(const s16x8 (&fr)[4][2], const s16x8 (&fi)[4][2],
    const char* Pr, const char* Pi, f32x4 (&qr)[2][4], f32x4 (&qi)[2][4],
    int wc, int l15, int hi){
  #pragma unroll
  for (int m=0;m<2;m++)
    #pragma unroll
    for (int n=0;n<4;n++){ qr[m][n] = (f32x4){0,0,0,0}; qi[m][n] = (f32x4){0,0,0,0}; }
  #pragma unroll
  for (int kk = 0; kk < 4; kk++){
    int kb = kk*32 + hi*8;
    #pragma unroll
    for (int n=0;n<4;n++){
      int c = wc + n*16 + l15;
      int o = swz16(c, kb*2);
      s16x8 b_r = *(const s16x8*)(Pr + o);
      s16x8 b_i = *(const s16x8*)(Pi + o);
      #pragma unroll
      for (int m=0;m<2;m++)
        cmfma<0,0>(fr[kk][m], fi[kk][m], b_r, b_i, qr[m][n], qi[m][n]);
    }
  }
}
__device__ __forceinline__ void pwrite16(char* Pr, char* Pi,
    f32x4 (&qr)[2][4], f32x4 (&qi)[2][4], float sc, int t){
  int wv = t>>6, lane = t&63, l15 = lane&15, hi = lane>>4;
  int wr = (wv>>1)*32, wc = (wv&1)*64;
  #pragma unroll
  for (int m=0;m<2;m++)
    #pragma unroll
    for (int n=0;n<4;n++){
      int c = wc + n*16 + l15, r0 = wr + m*16 + hi*4;
      uint2 pr, pi;
      pr.x = cvtpk(qr[m][n][0]*sc, qr[m][n][1]*sc);
      pr.y = cvtpk(qr[m][n][2]*sc, qr[m][n][3]*sc);
      pi.x = cvtpk(qi[m][n][0]*sc, qi[m][n][1]*sc);
      pi.y = cvtpk(qi[m][n][2]*sc, qi[m][n][3]*sc);
      int o = swz16(c, r0*2);
      *(uint2*)(Pr + o) = pr;
      *(uint2*)(Pi + o) = pi;
    }
}
// max-renorm into DEST buffers (dbuf-safe); one internal barrier
__device__ __forceinline__ int renorm_to(char* Pr, char* Pi, float* red,
    f32x4 (&qr)[2][4], f32x4 (&qi)[2][4], int t){
  int wv = t>>6, lane = t&63;
  float lm = 0.f;
  #pragma unroll
  for (int m=0;m<2;m++)
    #pragma unroll
    for (int n=0;n<4;n++)
      #pragma unroll
      for (int j=0;j<4;j++)
        lm = fmaxf(lm, fmaxf(fabsf(qr[m][n][j]), fabsf(qi[m][n][j])));
  #pragma unroll
  for (int o = 32; o > 0; o >>= 1) lm = fmaxf(lm, __shfl_xor(lm, o, 64));
  if (lane == 0) red[wv] = lm;
  __syncthreads();
  float mx = 0.f;
  #pragma unroll
  for (int i = 0; i < 8; i++) mx = fmaxf(mx, red[i]);
  int e = 0; if (mx > 0.f) frexpf(mx, &e);
  pwrite16(Pr, Pi, qr, qi, ldexpf(1.f, -e), t);
  return e;
}
__device__ __forceinline__ void stage_cols16(const u16* gr, const u16* gi,
                                             char* Pr, char* Pi, int t){
  #pragma unroll
  for (int i = 0; i < 4; i++){
    int chunk = t + i*512;
    int c = chunk >> 4, rr = chunk & 15;
    int o = swz16(c, rr*16);
    *(uint4*)(Pr + o) = *(const uint4*)(gr + c*128 + rr*8);
    *(uint4*)(Pi + o) = *(const uint4*)(gi + c*128 + rr*8);
  }
}
__device__ __forceinline__ void write_node16(u16* dr, u16* di,
    const char* Pr, const char* Pi, bool rowLayout, int t){
  if (!rowLayout){
    #pragma unroll
    for (int i = 0; i < 4; i++){
      int chunk = t + i*512;
      int c = chunk >> 4, rr = chunk & 15;
      int o = swz16(c, rr*16);
      *(uint4*)(dr + c*128 + rr*8) = *(const uint4*)(Pr + o);
      *(uint4*)(di + c*128 + rr*8) = *(const uint4*)(Pi + o);
    }
  } else {
    for (int idx = t; idx < MATN; idx += 512){
      int r = idx >> 7, c = idx & 127;
      int o = swz16(c, r*2);
      dr[idx] = *(const u16*)(Pr + o);
      di[idx] = *(const u16*)(Pi + o);
    }
  }
}

// ----------------- k_p2m: P2 = Ka @ Kb via bf16 MFMA -> bf16 planes ---------
__global__ __launch_bounds__(512) void k_p2m(WS w){
  __shared__ __align__(16) char P0r[32768];
  __shared__ __align__(16) char P0i[32768];
  __shared__ __align__(16) char P1r[32768];
  __shared__ __align__(16) char P1i[32768];
  int blk = blockIdx.x, a = blk >> 3, b = blk & 7;
  int t = threadIdx.x, wv = t>>6, lane = t&63, l15 = lane&15, hi = lane>>4;
  int wr = (wv>>1)*32, wc = (wv&1)*64;
  const u16* Bb = w.Kb + (size_t)(b*4 + 2)*MATN;
  stage_cols16(Bb, Bb + MATN, P0r, P0i, t);
  s16x8 Afr[4][2], Afi[4][2];
  const u16* Ab = w.Kb + (size_t)(a*4)*MATN;
  loadA(Ab, Ab + MATN, wr, l15, hi, Afr, Afi);
  __syncthreads();
  f32x4 qr[2][4], qi[2][4];
  ccomputeR(Afr, Afi, P0r, P0i, qr, qi, wc, l15, hi);
  pwrite16(P1r, P1i, qr, qi, 1.f/(1<<P2SH), t);
  __syncthreads();
  u16* base = w.P2b + (size_t)blk*4*MATN;
  write_node16(base + 2*MATN, base + 3*MATN, P1r, P1i, false, t);
  write_node16(base, base + MATN, P1r, P1i, true, t);
}

// chains: 256 blocks, 15 products; dbuf + single-set A prefetch + raw barrier
__global__ __launch_bounds__(512,1) void k_chain(WS w){
  __shared__ __align__(16) char P0r[32768];
  __shared__ __align__(16) char P0i[32768];
  __shared__ __align__(16) char P1r[32768];
  __shared__ __align__(16) char P1i[32768];
  __shared__ float red[8];
  int p = blockIdx.x, t = threadIdx.x;
  int wv = t>>6, lane = t&63, l15 = lane&15, hi = lane>>4;
  int wr = (wv>>1)*32, wc = (wv&1)*64;
  char *PrC = P0r, *PiC = P0i, *PrN = P1r, *PiN = P1i;
  int tok0 = w.tok[p*GLG];
  const u16* b0 = w.P2b + (size_t)tok0*4*MATN;
  stage_cols16(b0 + 2*MATN, b0 + 3*MATN, PrC, PiC, t);
  s16x8 Afr[4][2], Afi[4][2];
  { const u16* tb = w.P2b + (size_t)w.tok[p*GLG + 1]*4*MATN;
    loadA(tb, tb + MATN, wr, l15, hi, Afr, Afi); }
  f32x4 qr[2][4], qi[2][4];
  int eLast = 0;
  __syncthreads();
  #pragma unroll 1
  for (int s = 1; s < GLG; s++){
    ccomputeR(Afr, Afi, PrC, PiC, qr, qi, wc, l15, hi);
    if (s + 1 < GLG){
      const u16* tb = w.P2b + (size_t)w.tok[p*GLG + s + 1]*4*MATN;
      loadA(tb, tb + MATN, wr, l15, hi, Afr, Afi);   // issue early; waits at next use
    }
    if (s < GLG-1) pwrite16(PrN, PiN, qr, qi, 1.f/(1<<CHSH), t);
    else eLast = renorm_to(PrN, PiN, red, qr, qi, t);
    asm volatile("s_waitcnt lgkmcnt(0)" ::: "memory");  // LDS drained; vmem stays in flight
    __builtin_amdgcn_s_barrier();
    { char* x = PrC; PrC = PrN; PrN = x; x = PiC; PiC = PiN; PiN = x; }
  }
  u16* slot = w.nodes0 + (size_t)p*2*MATN;
  write_node16(slot, slot + MATN, PrC, PiC, (p & 3) != 0, t);
  if (t == 0) w.E0[p] = P2SH*GLG + CHSH*(GLG-2) + eLast;
}

// radix-4 level: dbuf + prefetch + raw barrier
__global__ __launch_bounds__(512,1) void k_level(WS w, int srcIs0, int isRoot){
  __shared__ __align__(16) char P0r[32768];
  __shared__ __align__(16) char P0i[32768];
  __shared__ __align__(16) char P1r[32768];
  __shared__ __align__(16) char P1i[32768];
  __shared__ float red[8];
  int p = blockIdx.x, t = threadIdx.x;
  int wv = t>>6, lane = t&63, l15 = lane&15, hi = lane>>4;
  int wr = (wv>>1)*32, wc = (wv&1)*64;
  char *PrC = P0r, *PiC = P0i, *PrN = P1r, *PiN = P1i;
  const u16* src = srcIs0 ? w.nodes0 : w.nodes1;
  u16* dst       = srcIs0 ? w.nodes1 : w.nodes0;
  const int* Es  = srcIs0 ? w.E0 : w.E1;
  int* Ed        = srcIs0 ? w.E1 : w.E0;
  const u16* B = src + (size_t)(4*p)*2*MATN;
  stage_cols16(B, B + MATN, PrC, PiC, t);
  s16x8 Afr[4][2], Afi[4][2];
  { const u16* A = src + (size_t)(4*p+1)*2*MATN;
    loadA(A, A + MATN, wr, l15, hi, Afr, Afi); }
  int E = Es[4*p] + Es[4*p+1] + Es[4*p+2] + Es[4*p+3];
  f32x4 qr[2][4], qi[2][4];
  __syncthreads();
  #pragma unroll 1
  for (int j = 1; j < 4; j++){
    ccomputeR(Afr, Afi, PrC, PiC, qr, qi, wc, l15, hi);
    if (j < 3){
      const u16* A = src + (size_t)(4*p + j + 1)*2*MATN;
      loadA(A, A + MATN, wr, l15, hi, Afr, Afi);
    }
    E += renorm_to(PrN, PiN, red, qr, qi, t);
    asm volatile("s_waitcnt lgkmcnt(0)" ::: "memory");
    __builtin_amdgcn_s_barrier();
    { char* x = PrC; PrC = PrN; PrN = x; x = PiC; PiC = PiN; PiN = x; }
  }
  u16* slot = dst + (size_t)p*2*MATN;
  write_node16(slot, slot + MATN, PrC, PiC, ((p & 3) != 0) || isRoot, t);
  if (t == 0) Ed[p] = E;
}

// -------- fused power iteration (R8 verbatim) --------
__global__ __launch_bounds__(512,1) void k_pow(WS w, int par){
  __shared__ __align__(16) char Rr[32768];
  __shared__ __align__(16) char Ri[32768];
  __shared__ __align__(16) char Yr[32768];
  __shared__ __align__(16) char Yi[32768];
  int b = blockIdx.x, side = b >> 3, rb = b & 7;
  int t = threadIdx.x, wv = t>>6, lane = t&63, l15 = lane&15, hi = lane>>4;
  const u16* rhoS = w.rho + (size_t)((par*2 + side)*2)*MATN;
  stage_cols16(rhoS, rhoS + MATN, Rr, Ri, t);
  __syncthreads();
  { int x = wv;
    const u16* Ab = w.Kb + (size_t)(x*4 + (side ? 2 : 0))*MATN;
    const u16* Ar = Ab; const u16* Ai = Ab + MATN;
    f32x4 q1r[8], q1i[8];
    #pragma unroll
    for (int n=0;n<8;n++){ q1r[n] = (f32x4){0,0,0,0}; q1i[n] = (f32x4){0,0,0,0}; }
    #pragma unroll
    for (int kk = 0; kk < 4; kk++){
      int kb = kk*32 + hi*8;
      int r = rb*16 + l15;
      s16x8 a_r = *(const s16x8*)(Ar + r*128 + kb);
      s16x8 a_i = *(const s16x8*)(Ai + r*128 + kb);
      #pragma unroll
      for (int n=0;n<8;n++){
        int c = n*16 + l15;
        int o = swz16(c, kb*2);
        s16x8 b_r = *(const s16x8*)(Rr + o);
        s16x8 b_i = *(const s16x8*)(Ri + o);
        if (side == 0) cmfma<0,0>(a_r, a_i, b_r, b_i, q1r[n], q1i[n]);
        else           cmfma<1,0>(a_r, a_i, b_r, b_i, q1r[n], q1i[n]);
      }
    }
    const float sc = 1.f/(1<<S1SH);
    #pragma unroll
    for (int n=0;n<8;n++)
      #pragma unroll
      for (int q=0;q<4;q++){
        int lr = hi*4 + q, c = n*16 + l15;
        *(u16*)(Yr + x*4096 + swz16(lr, c*2)) = f2bf(q1r[n][q]*sc);
        *(u16*)(Yi + x*4096 + swz16(lr, c*2)) = f2bf(q1i[n][q]*sc);
      }
  }
  __syncthreads();
  { int c0 = wv*16, c = c0 + l15;
    f32x4 q2r = {0,0,0,0}, q2i = {0,0,0,0};
    #pragma unroll 2
    for (int x = 0; x < 8; x++){
      const u16* Bb = w.Kb + (size_t)(x*4 + (side ? 2 : 0))*MATN;
      const u16* Br = Bb; const u16* Bi = Bb + MATN;
      #pragma unroll
      for (int kk = 0; kk < 4; kk++){
        int kb = kk*32 + hi*8;
        s16x8 a_r = *(const s16x8*)(Yr + x*4096 + swz16(l15, kb*2));
        s16x8 a_i = *(const s16x8*)(Yi + x*4096 + swz16(l15, kb*2));
        s16x8 b_r = *(const s16x8*)(Br + c*128 + kb);
        s16x8 b_i = *(const s16x8*)(Bi + c*128 + kb);
        if (side == 0) cmfma<0,1>(a_r, a_i, b_r, b_i, q2r, q2i);
        else           cmfma<0,0>(a_r, a_i, b_r, b_i, q2r, q2i);
      }
    }
    const float sc = 1.f/(1<<S2SH);
    u16* Dr = w.rho + (size_t)(((par^1)*2 + side)*2)*MATN;
    u16* Di = Dr + MATN;
    int r0g = rb*16 + hi*4;
    uint2 pr, pi;
    pr.x = cvtpk(q2r[0]*sc, q2r[1]*sc); pr.y = cvtpk(q2r[2]*sc, q2r[3]*sc);
    pi.x = cvtpk(q2i[0]*sc, q2i[1]*sc); pi.y = cvtpk(q2i[2]*sc, q2i[3]*sc);
    *(uint2*)(Dr + c*128 + r0g) = pr;
    *(uint2*)(Di + c*128 + r0g) = pi;
    if (side == 1 && wv == rb){
      float tr = 0.f;
      #pragma unroll
      for (int q=0;q<4;q++) if (hi*4 + q == l15) tr += q2r[q]*sc;
      #pragma unroll
      for (int o = 32; o > 0; o >>= 1) tr += __shfl_xor(tr, o, 64);
      if (lane == 0) w.trbuf[par*16 + 8 + rb] = tr;
    }
  }
}

// ----------------- fused epilogue (R8 verbatim) -----------------
__global__ __launch_bounds__(512) void k_epi(WS w){
  __shared__ __align__(16) char T1r[32768];
  __shared__ __align__(16) char T1i[32768];
  int t = threadIdx.x, wv = t>>6, lane = t&63, l15 = lane&15, hi = lane>>4;
  int wr = (wv>>2)*64, wc = (wv&3)*32;
  f32x4 qr[4][2], qi[4][2];
  const u16* Ar = w.rho;
  const u16* Ai = Ar + MATN;
  #pragma unroll
  for (int m=0;m<4;m++)
    #pragma unroll
    for (int n=0;n<2;n++){ qr[m][n] = (f32x4){0,0,0,0}; qi[m][n] = (f32x4){0,0,0,0}; }
  #pragma unroll
  for (int kk = 0; kk < 4; kk++){
    int kb = kk*32 + hi*8;
    #pragma unroll
    for (int m=0;m<4;m++){
      int r = wr + m*16 + l15;
      s16x8 a_r = *(const s16x8*)(Ar + r*128 + kb);
      s16x8 a_i = *(const s16x8*)(Ai + r*128 + kb);
      #pragma unroll
      for (int n=0;n<2;n++){
        int c = wc + n*16 + l15;
        s16x8 b_r = *(const s16x8*)(w.rootR + c*128 + kb);
        s16x8 b_i = *(const s16x8*)(w.rootI + c*128 + kb);
        cmfma<0,0>(a_r, a_i, b_r, b_i, qr[m][n], qi[m][n]);
      }
    }
  }
  {
    const float sc = 1.f/(1<<CHSH);
    #pragma unroll
    for (int m=0;m<4;m++)
      #pragma unroll
      for (int n=0;n<2;n++){
        int c = wc + n*16 + l15, r0 = wr + m*16 + hi*4;
        uint2 pr, pi;
        pr.x = cvtpk(qr[m][n][0]*sc, qr[m][n][1]*sc);
        pr.y = cvtpk(qr[m][n][2]*sc, qr[m][n][3]*sc);
        pi.x = cvtpk(qi[m][n][0]*sc, qi[m][n][1]*sc);
        pi.y = cvtpk(qi[m][n][2]*sc, qi[m][n][3]*sc);
        int o = swz16(c, r0*2);
        *(uint2*)(T1r + o) = pr;
        *(uint2*)(T1i + o) = pi;
      }
  }
  __syncthreads();
  #pragma unroll
  for (int m=0;m<4;m++)
    #pragma unroll
    for (int n=0;n<2;n++){ qr[m][n] = (f32x4){0,0,0,0}; qi[m][n] = (f32x4){0,0,0,0}; }
  #pragma unroll
  for (int kk = 0; kk < 4; kk++){
    int kb = kk*32 + hi*8;
    #pragma unroll
    for (int m=0;m<4;m++){
      int r = wr + m*16 + l15;
      int o = swz16(r, kb*2);
      s16x8 a_r = *(const s16x8*)(T1r + o);
      s16x8 a_i = *(const s16x8*)(T1i + o);
      #pragma unroll
      for (int n=0;n<2;n++){
        int c = wc + n*16 + l15;
        s16x8 b_r = *(const s16x8*)(w.rootR + c*128 + kb);
        s16x8 b_i = *(const s16x8*)(w.rootI + c*128 + kb);
        cmfma<0,1>(a_r, a_i, b_r, b_i, qr[m][n], qi[m][n]);
      }
    }
  }
  __syncthreads();
  double* red = (double*)T1r;
  const u16* rlr = w.rho + (size_t)2*MATN;
  const u16* rli = rlr + MATN;
  double a1 = 0.0;
  #pragma unroll
  for (int m=0;m<4;m++)
    #pragma unroll
    for (int n=0;n<2;n++){
      int c = wc + n*16 + l15, r0 = wr + m*16 + hi*4;
      #pragma unroll
      for (int q=0;q<4;q++){
        int r = r0 + q;
        float lr = bf2f(rlr[r*128 + c]), li = bf2f(rli[r*128 + c]);
        a1 += (double)qr[m][n][q]*lr - (double)qi[m][n][q]*li;
      }
    }
  red[t] = a1; __syncthreads();
  for (int o = 256; o > 0; o >>= 1){ if (t < o) red[t] += red[t+o]; __syncthreads(); }
  double that = red[0]; __syncthreads();
  const u16* rrr = w.rho;
  const u16* rri = rrr + MATN;
  double a2 = 0.0;
  for (int idx = t; idx < MATN; idx += 512){
    int c = idx >> 7, r = idx & 127;
    float ar_ = bf2f(rrr[idx]), ai_ = bf2f(rri[idx]);
    float lr  = bf2f(rlr[r*128 + c]), li = bf2f(rli[r*128 + c]);
    a2 += (double)ar_*lr - (double)ai_*li;
  }
  red[t] = a2; __syncthreads();
  for (int o = 256; o > 0; o >>= 1){ if (t < o) red[t] += red[t+o]; __syncthreads(); }
  double trrl = red[0];
  if (t == 0){
    double T0 = 0.0, T1s = 0.0;
    for (int s = 0; s < 8; s++){ T0 += w.trbuf[8+s]; T1s += w.trbuf[16+8+s]; }
    double lam = ldexp(T1s / T0, S1SH + S2SH);
    double logp = (double)LSEQ * log2(lam) - 2.0*(double)w.Eroot[0] - (double)CHSH
                  - log2(fmax(that, 1e-300)) + log2(fmax(trrl, 1e-300));
    w.out[0] = (float)logp;
  }
}

// ----------------- host -----------------
static inline size_t aln256(size_t x){ return (x + 255) & ~(size_t)255; }

extern "C" void kernel_launch(void* const* d_in, const int* in_sizes, int n_in,
                              void* d_out, int out_size, void* d_ws, size_t ws_size,
                              hipStream_t stream){
  const float* Kre = (const float*)d_in[0];
  const float* Kim = (const float*)d_in[1];
  const int*   seq = (const int*)d_in[2];

  WS w{};
  char* p = (char*)d_ws;
  auto take = [&](size_t bytes)->char*{ char* r = p; p += aln256(bytes); return r; };
  w.Kb    = (u16*)take((size_t)NA*4*MATN*2);
  w.P2b   = (u16*)take((size_t)64*4*MATN*2);
  w.rho   = (u16*)take((size_t)8*MATN*2);
  w.nodes0= (u16*)take((size_t)GCH*2*MATN*2);
  w.nodes1= (u16*)take((size_t)(GCH/4)*2*MATN*2);
  w.tok   = (int*)take(NTOK*4);
  w.E0    = (int*)take(GCH*4);
  w.E1    = (int*)take(GCH*4);
  w.trbuf = (float*)take(32*4);
  w.out = (float*)d_out;
  // levels: 256 ->64(n0->n1) ->16(n1->n0) ->4(n0->n1) ->1(n1->n0, root)
  w.rootR = w.nodes0; w.rootI = w.nodes0 + MATN;
  w.Eroot = w.E0;

  hipLaunchKernelGGL(k_kbinit, dim3(NA*16), dim3(256), 0, stream, Kre, Kim, seq, w);
  hipLaunchKernelGGL(k_p2m, dim3(64), dim3(512), 0, stream, w);
  hipLaunchKernelGGL(k_chain, dim3(GCH), dim3(512), 0, stream, w);
  hipLaunchKernelGGL(k_level, dim3(64), dim3(512), 0, stream, w, 1, 0);
  hipLaunchKernelGGL(k_level, dim3(16), dim3(512), 0, stream, w, 0, 0);
  hipLaunchKernelGGL(k_level, dim3(4),  dim3(512), 0, stream, w, 1, 0);
  hipLaunchKernelGGL(k_level, dim3(1),  dim3(512), 0, stream, w, 0, 1);
  for (int k = 0; k < PITERS; k++)
    hipLaunchKernelGGL(k_pow, dim3(16), dim3(512), 0, stream, w, k & 1);
  hipLaunchKernelGGL(k_epi, dim3(1), dim3(512), 0, stream, w);
}